// Round 2
// baseline (148.999 us; speedup 1.0000x reference)
//
#include <hip/hip_runtime.h>
#include <hip/hip_bf16.h>

typedef __hip_bfloat16 bf16;
typedef __attribute__((ext_vector_type(8))) short short8;
typedef __attribute__((ext_vector_type(4))) short short4_;
typedef __attribute__((ext_vector_type(4))) float f32x4;

#define MFMA16(a, b, c) __builtin_amdgcn_mfma_f32_16x16x32_bf16((a), (b), (c), 0, 0, 0)

// Problem constants
#define BATCH 2
#define NQ 2048
#define NKV 2048
#define HEADS 8
#define DHEAD 64
#define CQ 1024
#define CK 768
#define IDIM 512   // HEADS*DHEAD
#define SCALE 0.125f

__device__ __forceinline__ short8 ld8(const bf16* p) {
    return *(const short8*)p;
}

// async global->LDS, 16 bytes per lane. LDS dst must be wave-uniform base + lane*16.
__device__ __forceinline__ void async_ld16(const bf16* g, bf16* l) {
    __builtin_amdgcn_global_load_lds((__attribute__((address_space(1))) const void*)g,
                                     (__attribute__((address_space(3))) void*)l,
                                     16, 0, 0);
}

__device__ __forceinline__ unsigned int pk2(float a, float b) {
    union { bf16 h[2]; unsigned int u; } x;
    x.h[0] = __float2bfloat16(a);
    x.h[1] = __float2bfloat16(b);
    return x.u;
}

// ---------------------------------------------------------------------------
// Prologue: fp32->bf16 activation pack (blocks 0..3583, 8 floats/thread) +
// tiled weight transpose fp32(R,C) -> bf16(C,R) (blocks 3584..4031).
// ---------------------------------------------------------------------------
__global__ __launch_bounds__(256) void prologue(
    const float* __restrict__ x, const float* __restrict__ ctx,
    const float* __restrict__ Wq, const float* __restrict__ Wk,
    const float* __restrict__ Wv, const float* __restrict__ Wo,
    bf16* __restrict__ Xb, bf16* __restrict__ Cb,
    bf16* __restrict__ WqT, bf16* __restrict__ WkT,
    bf16* __restrict__ WvT, bf16* __restrict__ WoT) {
    __shared__ float tile[64][65];
    const int t = threadIdx.x;
    const int bx = blockIdx.x;

    if (bx < 3584) {
        int idx = bx * 256 + t;
        const int NX8 = (4096 * 1024) / 8;      // 524,288
        const float4* srcp;
        bf16* dstp;
        if (idx < NX8) {
            srcp = (const float4*)x + (size_t)idx * 2;
            dstp = Xb + (size_t)idx * 8;
        } else {
            int j = idx - NX8;                  // < 393,216
            srcp = (const float4*)ctx + (size_t)j * 2;
            dstp = Cb + (size_t)j * 8;
        }
        float4 v0 = srcp[0], v1 = srcp[1];
        bf16 tmp[8] = {__float2bfloat16(v0.x), __float2bfloat16(v0.y),
                       __float2bfloat16(v0.z), __float2bfloat16(v0.w),
                       __float2bfloat16(v1.x), __float2bfloat16(v1.y),
                       __float2bfloat16(v1.z), __float2bfloat16(v1.w)};
        *(short8*)dstp = *(short8*)tmp;
        return;
    }

    int tb = bx - 3584;   // 0..447
    const float* src; bf16* dst; int R, C, ti;
    if (tb < 128)      { src = Wq; dst = WqT; R = 1024; C = 512;  ti = tb; }
    else if (tb < 224) { src = Wk; dst = WkT; R = 768;  C = 512;  ti = tb - 128; }
    else if (tb < 320) { src = Wv; dst = WvT; R = 768;  C = 512;  ti = tb - 224; }
    else               { src = Wo; dst = WoT; R = 512;  C = 1024; ti = tb - 320; }
    const int tilesC = C >> 6;
    const int tr = ti / tilesC, tc = ti - tr * tilesC;

    {
        int row = t >> 4;
        int c4 = (t & 15) * 4;
#pragma unroll
        for (int p = 0; p < 4; ++p) {
            float4 v = *(const float4*)&src[(size_t)(tr * 64 + p * 16 + row) * C + tc * 64 + c4];
            tile[p * 16 + row][c4 + 0] = v.x;
            tile[p * 16 + row][c4 + 1] = v.y;
            tile[p * 16 + row][c4 + 2] = v.z;
            tile[p * 16 + row][c4 + 3] = v.w;
        }
    }
    __syncthreads();
    {
        int oc = t >> 2;
        int r0 = (t & 3) * 16;
        bf16 tmp[16];
#pragma unroll
        for (int j = 0; j < 16; ++j)
            tmp[j] = __float2bfloat16(tile[r0 + j][oc]);
        bf16* dp = dst + (size_t)(tc * 64 + oc) * R + tr * 64 + r0;
        *(short8*)dp = *(short8*)&tmp[0];
        *(short8*)(dp + 8) = *(short8*)&tmp[8];
    }
}

// ---------------------------------------------------------------------------
// Fused Q/K/V projection GEMM, 64x128 tiles, BK=64, XOR-swizzled LDS chunks,
// double-buffered. blockIdx.z: 0 -> Q, 1 -> K, 2 -> V^T epilogue.
// LDS-staged coalesced epilogue for all z (short8 stores; z=2 transposes
// in LDS so each 64B Vt line is written by one thread instead of a 2B scatter)
// ---------------------------------------------------------------------------
__global__ __launch_bounds__(256) void qkv_gemm(
    const bf16* __restrict__ Xb, const bf16* __restrict__ Cb,
    const bf16* __restrict__ WqT, const bf16* __restrict__ WkT,
    const bf16* __restrict__ WvT,
    bf16* __restrict__ Qb, bf16* __restrict__ Kb, bf16* __restrict__ Vt) {
    __shared__ char SMEM[49152];               // At 16K + Bts 32K; epilogue aliases base
    bf16* At  = (bf16*)SMEM;                   // [2][64*64]
    bf16* Bts = (bf16*)(SMEM + 16384);         // [2][128*64]
    bf16* Ep  = (bf16*)SMEM;                   // epilogue: z<2 [64][136], z=2 [128][72]

    const int z = blockIdx.z;
    const bf16* A  = (z == 0) ? Xb : Cb;
    const bf16* Bt = (z == 0) ? WqT : (z == 1) ? WkT : WvT;
    const int K = (z == 0) ? 1024 : 768;

    const int t = threadIdx.x;
    const int wave = t >> 6;
    const int lane = t & 63;
    const int n15 = lane & 15;
    const int quad = lane >> 4;
    const int wm = wave >> 1;
    const int wn = wave & 1;
    const int bm = blockIdx.y;     // 0..63
    const int bn = blockIdx.x;     // 0..3

    f32x4 acc[2][4] = {};

    const bf16* Ablk = A + (size_t)bm * 64 * K;
    const bf16* Bblk = Bt + (size_t)bn * 128 * K;

    int ar[2], ac[2], br[4], bc[4];
#pragma unroll
    for (int i = 0; i < 2; ++i) {
        int g = i * 256 + t;
        ar[i] = g >> 3; ac[i] = ((g & 7) ^ (ar[i] & 7)) * 8;
    }
#pragma unroll
    for (int i = 0; i < 4; ++i) {
        int g = i * 256 + t;
        br[i] = g >> 3; bc[i] = ((g & 7) ^ (br[i] & 7)) * 8;
    }

#pragma unroll
    for (int i = 0; i < 2; ++i)
        async_ld16(Ablk + ar[i] * K + ac[i], At + (i * 256 + t) * 8);
#pragma unroll
    for (int i = 0; i < 4; ++i)
        async_ld16(Bblk + br[i] * K + bc[i], Bts + (i * 256 + t) * 8);
    __syncthreads();

    for (int k0 = 0; k0 < K; k0 += 64) {
        const int p = (k0 >> 6) & 1;
        if (k0 + 64 < K) {
            const int q = p ^ 1;
            const int kn = k0 + 64;
#pragma unroll
            for (int i = 0; i < 2; ++i)
                async_ld16(Ablk + ar[i] * K + kn + ac[i], At + q * 4096 + (i * 256 + t) * 8);
#pragma unroll
            for (int i = 0; i < 4; ++i)
                async_ld16(Bblk + br[i] * K + kn + bc[i], Bts + q * 8192 + (i * 256 + t) * 8);
        }

#pragma unroll
        for (int kh = 0; kh < 2; ++kh) {
            short8 af[2], bfr[4];
#pragma unroll
            for (int mt = 0; mt < 2; ++mt) {
                int R = wm * 32 + mt * 16 + n15;
                af[mt] = ld8(At + p * 4096 + R * 64 + (((kh * 4 + quad) ^ (R & 7)) * 8));
            }
#pragma unroll
            for (int nt = 0; nt < 4; ++nt) {
                int R = wn * 64 + nt * 16 + n15;
                bfr[nt] = ld8(Bts + p * 8192 + R * 64 + (((kh * 4 + quad) ^ (R & 7)) * 8));
            }
#pragma unroll
            for (int mt = 0; mt < 2; ++mt)
#pragma unroll
                for (int nt = 0; nt < 4; ++nt)
                    acc[mt][nt] = MFMA16(af[mt], bfr[nt], acc[mt][nt]);
        }

        __syncthreads();
    }

    // -------- epilogue: stage to LDS, store coalesced (short8) --------
    if (z < 2) {
        // row-major [64][136] (272B rows -> 16B aligned)
#pragma unroll
        for (int mt = 0; mt < 2; ++mt)
#pragma unroll
            for (int nt = 0; nt < 4; ++nt) {
                int col = wn * 64 + nt * 16 + n15;
#pragma unroll
                for (int r = 0; r < 4; ++r) {
                    int row = wm * 32 + mt * 16 + quad * 4 + r;
                    Ep[row * 136 + col] = __float2bfloat16(acc[mt][nt][r]);
                }
            }
    } else {
        // transposed [128 cols][72] so j is contiguous for Vt
#pragma unroll
        for (int mt = 0; mt < 2; ++mt)
#pragma unroll
            for (int nt = 0; nt < 4; ++nt) {
                int col = wn * 64 + nt * 16 + n15;
#pragma unroll
                for (int r = 0; r < 4; ++r) {
                    int row = wm * 32 + mt * 16 + quad * 4 + r;
                    Ep[col * 72 + row] = __float2bfloat16(acc[mt][nt][r]);
                }
            }
    }
    __syncthreads();

    bf16* C = (z == 0) ? Qb : (z == 1) ? Kb : Vt;
    if (z < 2) {
#pragma unroll
        for (int i = 0; i < 4; ++i) {
            int idx = i * 256 + t;
            int row = idx >> 4, seg = idx & 15;
            short8 v = ld8(&Ep[row * 136 + seg * 8]);
            *(short8*)&C[(size_t)(bm * 64 + row) * 512 + bn * 128 + seg * 8] = v;
        }
    } else {
        const int bb = bm >> 5;   // batch of this 64-row block (64 rows | 2048/batch)
#pragma unroll
        for (int i = 0; i < 4; ++i) {
            int idx = i * 256 + t;
            int col = idx >> 3, seg = idx & 7;
            int cg = bn * 128 + col;
            int hh = cg >> 6, dd = cg & 63;
            int jrow = (bm & 31) * 64 + seg * 8;   // within-batch key index (FIX)
            short8 v = ld8(&Ep[col * 72 + seg * 8]);
            *(short8*)&C[(size_t)(((bb << 3) + hh) * 64 + dd) * 2048 + jrow] = v;
        }
    }
}

// ---------------------------------------------------------------------------
// Final GEMM: out(4096,1024) = Ob(4096,512) @ WoT(1024,512)^T + bo, fp32 out.
// 64x128 tiles, BK=64, swizzled, double-buffered + coalesced fp32 epilogue
// via LDS transpose (aliased over At/Bts, stride 132 = 2-way free).
// ---------------------------------------------------------------------------
__global__ __launch_bounds__(256) void out_gemm(const bf16* __restrict__ A,
                                                const bf16* __restrict__ Bt,
                                                const float* __restrict__ bias,
                                                float* __restrict__ C) {
    const int K = 512, N = 1024;
    __shared__ char SMEM[49152];               // 48 KB: At 16 + Bts 32
    bf16* At  = (bf16*)SMEM;                   // [2][64*64]
    bf16* Bts = (bf16*)(SMEM + 16384);         // [2][128*64]
    float* Ep = (float*)SMEM;                  // epilogue: [64][132] = 33.8 KB

    const int t = threadIdx.x;
    const int wave = t >> 6;
    const int lane = t & 63;
    const int n15 = lane & 15;
    const int quad = lane >> 4;
    const int wm = wave >> 1;
    const int wn = wave & 1;
    const int bm = blockIdx.y;     // 0..63
    const int bn = blockIdx.x;     // 0..7

    f32x4 acc[2][4] = {};

    const bf16* Ablk = A + (size_t)bm * 64 * K;
    const bf16* Bblk = Bt + (size_t)bn * 128 * K;

    int ar[2], ac[2], br[4], bc[4];
#pragma unroll
    for (int i = 0; i < 2; ++i) {
        int g = i * 256 + t;
        ar[i] = g >> 3; ac[i] = ((g & 7) ^ (ar[i] & 7)) * 8;
    }
#pragma unroll
    for (int i = 0; i < 4; ++i) {
        int g = i * 256 + t;
        br[i] = g >> 3; bc[i] = ((g & 7) ^ (br[i] & 7)) * 8;
    }

#pragma unroll
    for (int i = 0; i < 2; ++i)
        async_ld16(Ablk + ar[i] * K + ac[i], At + (i * 256 + t) * 8);
#pragma unroll
    for (int i = 0; i < 4; ++i)
        async_ld16(Bblk + br[i] * K + bc[i], Bts + (i * 256 + t) * 8);
    __syncthreads();

    for (int k0 = 0; k0 < K; k0 += 64) {
        const int p = (k0 >> 6) & 1;
        if (k0 + 64 < K) {
            const int q = p ^ 1;
            const int kn = k0 + 64;
#pragma unroll
            for (int i = 0; i < 2; ++i)
                async_ld16(Ablk + ar[i] * K + kn + ac[i], At + q * 4096 + (i * 256 + t) * 8);
#pragma unroll
            for (int i = 0; i < 4; ++i)
                async_ld16(Bblk + br[i] * K + kn + bc[i], Bts + q * 8192 + (i * 256 + t) * 8);
        }

#pragma unroll
        for (int kh = 0; kh < 2; ++kh) {
            short8 af[2], bfr[4];
#pragma unroll
            for (int mt = 0; mt < 2; ++mt) {
                int R = wm * 32 + mt * 16 + n15;
                af[mt] = ld8(At + p * 4096 + R * 64 + (((kh * 4 + quad) ^ (R & 7)) * 8));
            }
#pragma unroll
            for (int nt = 0; nt < 4; ++nt) {
                int R = wn * 64 + nt * 16 + n15;
                bfr[nt] = ld8(Bts + p * 8192 + R * 64 + (((kh * 4 + quad) ^ (R & 7)) * 8));
            }
#pragma unroll
            for (int mt = 0; mt < 2; ++mt)
#pragma unroll
                for (int nt = 0; nt < 4; ++nt)
                    acc[mt][nt] = MFMA16(af[mt], bfr[nt], acc[mt][nt]);
        }

        __syncthreads();
    }

    // stage fp32 tile to LDS (MFMA C-layout -> row-major), stride 132
#pragma unroll
    for (int mt = 0; mt < 2; ++mt)
#pragma unroll
        for (int nt = 0; nt < 4; ++nt) {
            int col = wn * 64 + nt * 16 + n15;
#pragma unroll
            for (int r = 0; r < 4; ++r) {
                int row = wm * 32 + mt * 16 + quad * 4 + r;
                Ep[row * 132 + col] = acc[mt][nt][r];
            }
        }
    __syncthreads();

    // coalesced store: 8 float4 per thread, consecutive lanes -> consecutive 16B
#pragma unroll
    for (int i = 0; i < 8; ++i) {
        int f4 = i * 256 + t;
        int row = f4 >> 5;            // 0..63
        int c4 = (f4 & 31) * 4;       // 0..124
        float4 v = *(float4*)&Ep[row * 132 + c4];
        float4 bv = *(const float4*)&bias[bn * 128 + c4];
        v.x += bv.x; v.y += bv.y; v.z += bv.z; v.w += bv.w;
        *(float4*)&C[(size_t)(bm * 64 + row) * N + bn * 128 + c4] = v;
    }
}

// ---------------------------------------------------------------------------
// Flash attention:
//  - double-buffered K/V tiles (64 KB LDS, 2 blocks/CU), ONE barrier per
//    64-key iteration, prefetch-after-barrier so global->LDS latency hides
//    under QK/softmax/PV of the current tile.
//  - P kept fully in registers: PV B-fragment slot (k = quad*8+j) is filled
//    with the keys this lane already owns from the S^T C-layout
//    (key = su*16 + quad*4 + r); the PV key order is permuted consistently
//    on the V side via paired ds_read_b64 at matching half-chunks.
//  Q:(b,i,h,d)  K:(b,j,h,d)  Vt:(b,h,d,j)  O:(b,i,h,d)
// ---------------------------------------------------------------------------
__global__ __launch_bounds__(512, 4) void flash_attn(const bf16* __restrict__ Q,
                                                     const bf16* __restrict__ K,
                                                     const bf16* __restrict__ Vt,
                                                     bf16* __restrict__ O) {
    __shared__ bf16 Kt[2][2][64 * 64];      // [buf][khalf] swizzled K tile (32 KB)
    __shared__ bf16 Vte[2][2][64 * 64];     // [buf][khalf] swizzled V^T tile (32 KB)
    // epilogue aliases (only touched after the post-loop barrier):
    float* Oc = (float*)&Kt[0][0][0];                    // [4][64][16] fp32 partial O
    float* Lc = (float*)((char*)&Kt[0][0][0] + 16384);   // [4][16] partial l
    bf16*  Pe = &Vte[0][0][0];                           // [4][16*72] O staging

    const int t = threadIdx.x;
    const int wave = t >> 6;            // 0..7
    const int g = wave >> 1;            // q-group 0..3
    const int khalf = wave & 1;         // key half
    const int lane = t & 63;
    const int n15 = lane & 15;
    const int quad = lane >> 4;

    const int L = blockIdx.x;           // 0..511
    const int bh = L & 15;              // XCD = L%8 -> bh%8: 2 (b,h) per XCD
    const int b = bh >> 3, h = bh & 7;
    const int q0 = (L >> 4) * 64;
    const int qw = q0 + g * 16;

    const bf16* Qp = Q + ((size_t)(b * NQ + qw) * IDIM + h * DHEAD);
    const bf16* Kp = K + ((size_t)b * NKV * IDIM + h * DHEAD)
                       + (size_t)(khalf * 1024) * IDIM;
    const bf16* Vp = Vt + (size_t)((b * HEADS + h) * DHEAD) * NKV + khalf * 1024;

    // Q fragments (B-operand): B[n=q=lane&15][k=d=quad*8+j], two 32-d halves
    short8 qa0 = ld8(Qp + n15 * IDIM + quad * 8);
    short8 qa1 = ld8(Qp + n15 * IDIM + 32 + quad * 8);

    // staging (256 lanes per half): slot s -> row r = s>>3, chunk c = (s&7)^(r&7)
    const int s0 = g * 128 + lane;
    const int s1 = s0 + 64;
    const int r0 = s0 >> 3, c0 = (s0 & 7) ^ (r0 & 7);
    const int r1 = s1 >> 3, c1 = (s1 & 7) ^ (r1 & 7);
    const bf16* kg0 = Kp + r0 * IDIM + c0 * 8;
    const bf16* kg1 = Kp + r1 * IDIM + c1 * 8;
    const bf16* vg0 = Vp + (size_t)r0 * NKV + c0 * 8;
    const bf16* vg1 = Vp + (size_t)r1 * NKV + c1 * 8;

    f32x4 o[4] = {};
    float lsum = 0.f;
    const int sw = n15 & 7;
    const int qh = quad >> 1;           // half-chunk select for paired V reads
    const int qb = (quad & 1) << 2;     // 4-elem offset within chunk

    // prologue: stage tile 0 into buf 0
    async_ld16(kg0, &Kt[0][khalf][s0 * 8]);
    async_ld16(kg1, &Kt[0][khalf][s1 * 8]);
    async_ld16(vg0, &Vte[0][khalf][s0 * 8]);
    async_ld16(vg1, &Vte[0][khalf][s1 * 8]);

    for (int it = 0; it < 16; ++it) {
        const int cur = it & 1;
        // current tile's DMA must have landed (drain), everyone off buf[cur^1]
        asm volatile("s_waitcnt vmcnt(0)" ::: "memory");
        __syncthreads();
        if (it < 15) {
            const int kn = (it + 1) * 64;
            async_ld16(kg0 + (size_t)kn * IDIM, &Kt[cur ^ 1][khalf][s0 * 8]);
            async_ld16(kg1 + (size_t)kn * IDIM, &Kt[cur ^ 1][khalf][s1 * 8]);
            async_ld16(vg0 + kn, &Vte[cur ^ 1][khalf][s0 * 8]);
            async_ld16(vg1 + kn, &Vte[cur ^ 1][khalf][s1 * 8]);
        }

        // S^T = K * Q^T : A=K frag A[m=key16][k=d], B=Q. 4 key-subtiles.
        f32x4 s[4] = {};
#pragma unroll
        for (int su = 0; su < 4; ++su) {
            const bf16* kr = &Kt[cur][khalf][(su * 16 + n15) * 64];
            short8 ka0 = ld8(kr + ((quad ^ sw) * 8));
            short8 ka1 = ld8(kr + (((4 + quad) ^ sw) * 8));
            s[su] = MFMA16(ka0, qa0, s[su]);
            s[su] = MFMA16(ka1, qa1, s[su]);
        }

        // p = exp(s*SCALE); pack to bf16 pairs fully in-register.
        // lane holds P^T[key = su*16 + quad*4 + r][q = n15]
        unsigned int w[4][2];
#pragma unroll
        for (int su = 0; su < 4; ++su) {
            float p0 = __expf(s[su][0] * SCALE);
            float p1 = __expf(s[su][1] * SCALE);
            float p2 = __expf(s[su][2] * SCALE);
            float p3 = __expf(s[su][3] * SCALE);
            lsum += (p0 + p1) + (p2 + p3);
            w[su][0] = pk2(p0, p1);
            w[su][1] = pk2(p2, p3);
        }
        // PV B-operand with permuted key order sigma(quad,j):
        //   pb0: keys {4q..4q+3 (su0), 16+4q..16+4q+3 (su1)}  (32-key half A)
        //   pb1: keys {32+4q.. (su2), 48+4q.. (su3)}           (32-key half B)
        union { short8 v; unsigned int u[4]; } pb0, pb1;
        pb0.u[0] = w[0][0]; pb0.u[1] = w[0][1]; pb0.u[2] = w[1][0]; pb0.u[3] = w[1][1];
        pb1.u[0] = w[2][0]; pb1.u[1] = w[2][1]; pb1.u[2] = w[3][0]; pb1.u[3] = w[3][1];

        // O^T += V^T * P^T : A=V frag A[m=d16][k], V columns fetched in the
        // SAME permuted key order via paired b64 reads at half-chunks.
#pragma unroll
        for (int d4 = 0; d4 < 4; ++d4) {
            const bf16* vr = &Vte[cur][khalf][(d4 * 16 + n15) * 64];
            union { short8 v; short4_ hh[2]; } va0, va1;
            va0.hh[0] = *(const short4_*)(vr + (((qh    ) ^ sw) << 3) + qb); // keys 4q+0..3
            va0.hh[1] = *(const short4_*)(vr + (((qh | 2) ^ sw) << 3) + qb); // keys 16+4q
            va1.hh[0] = *(const short4_*)(vr + (((qh | 4) ^ sw) << 3) + qb); // keys 32+4q
            va1.hh[1] = *(const short4_*)(vr + (((qh | 6) ^ sw) << 3) + qb); // keys 48+4q
            o[d4] = MFMA16(va0.v, pb0.v, o[d4]);
            o[d4] = MFMA16(va1.v, pb1.v, o[d4]);
        }
        // no trailing barrier: next iteration's barrier protects buf swap
    }

    // per-wave l reduction over quads -> all lanes of same n15 hold l[q]
    lsum += __shfl_xor(lsum, 16, 64);
    lsum += __shfl_xor(lsum, 32, 64);

    __syncthreads();   // all waves done with K/V tiles; safe to alias LDS

    // combine key halves (additive partials — no max subtraction)
    if (khalf == 1) {
#pragma unroll
        for (int d4 = 0; d4 < 4; ++d4)
#pragma unroll
            for (int r = 0; r < 4; ++r)
                Oc[(g * 64 + d4 * 16 + quad * 4 + r) * 16 + n15] = o[d4][r];
        if (quad == 0) Lc[g * 16 + n15] = lsum;
    }
    __syncthreads();
    if (khalf == 0) {
        float lt = lsum + Lc[g * 16 + n15];
        float inv = 1.0f / lt;
#pragma unroll
        for (int d4 = 0; d4 < 4; ++d4) {
            bf16 pk[4];
#pragma unroll
            for (int r = 0; r < 4; ++r) {
                float v = o[d4][r] + Oc[(g * 64 + d4 * 16 + quad * 4 + r) * 16 + n15];
                pk[r] = __float2bfloat16(v * inv);
            }
            *(uint2*)&Pe[g * (16 * 72) + n15 * 72 + d4 * 16 + quad * 4] = *(uint2*)pk;
        }
    }
    __syncthreads();

    // coalesced O store: thread t -> q_local = t>>3 (64 rows), 8 d-elems (16B)
    {
        int ql = t >> 3, seg = t & 7;
        const bf16* src = &Pe[(ql >> 4) * (16 * 72) + (ql & 15) * 72 + seg * 8];
        short8 a0 = ld8(src);
        bf16* dst = O + ((size_t)(b * NQ + q0 + ql) * IDIM + h * DHEAD + seg * 8);
        *(short8*)dst = a0;
    }
}

// ---------------------------------------------------------------------------
extern "C" void kernel_launch(void* const* d_in, const int* in_sizes, int n_in,
                              void* d_out, int out_size, void* d_ws, size_t ws_size,
                              hipStream_t stream) {
    (void)in_sizes; (void)n_in; (void)out_size; (void)ws_size;

    const float* x   = (const float*)d_in[0];   // (2,2048,1024)
    const float* ctx = (const float*)d_in[1];   // (2,2048,768)
    const float* Wq  = (const float*)d_in[2];   // (1024,512)
    const float* Wk  = (const float*)d_in[3];   // (768,512)
    const float* Wv  = (const float*)d_in[4];   // (768,512)
    const float* Wo  = (const float*)d_in[5];   // (512,1024)
    const float* bo  = (const float*)d_in[6];   // (1024,)
    float* out = (float*)d_out;                 // (2,2048,1024) fp32

    char* ws = (char*)d_ws;
    bf16* Xb  = (bf16*)(ws + 0);           // 4096x1024 bf16 : 8,388,608 B
    bf16* Cb  = (bf16*)(ws + 8388608);     // 4096x768  bf16 : 6,291,456 B
    bf16* WqT = (bf16*)(ws + 14680064);    //  512x1024 : 1,048,576 B
    bf16* WkT = (bf16*)(ws + 15728640);    //  512x768  :   786,432 B
    bf16* WvT = (bf16*)(ws + 16515072);    //  512x768  :   786,432 B
    bf16* WoT = (bf16*)(ws + 17301504);    // 1024x512  : 1,048,576 B
    bf16* Qb  = (bf16*)(ws + 18350080);    // 4096x512  : 4,194,304 B
    bf16* Kb  = (bf16*)(ws + 22544384);    // 4096x512  : 4,194,304 B
    bf16* Vt  = (bf16*)(ws + 26738688);    // (2,8,64,2048) : 4,194,304 B
    bf16* Ob  = (bf16*)(ws + 30932992);    // 4096x512  : 4,194,304 B
    // total 35,127,296 B

    prologue<<<4032, 256, 0, stream>>>(x, ctx, Wq, Wk, Wv, Wo,
                                       Xb, Cb, WqT, WkT, WvT, WoT);

    // Q/K/V projections: 64x128 tiles, BK=64, 768 blocks, double-buffered
    qkv_gemm<<<dim3(4, 64, 3), 256, 0, stream>>>(Xb, Cb, WqT, WkT, WvT, Qb, Kb, Vt);

    // attention: 512 blocks x 512 threads (8 waves: 4 q-groups x 2 key-halves)
    flash_attn<<<512, 512, 0, stream>>>(Qb, Kb, Vt, Ob);

    // out = O @ Wo + bo, fp32: 64x128 tiles, BK=64, 512 blocks
    out_gemm<<<dim3(8, 64), 256, 0, stream>>>(Ob, WoT, bo, out);
}

// Round 3
// 148.517 us; speedup vs baseline: 1.0032x; 1.0032x over previous
//
#include <hip/hip_runtime.h>
#include <hip/hip_bf16.h>

typedef __hip_bfloat16 bf16;
typedef __attribute__((ext_vector_type(8))) short short8;
typedef __attribute__((ext_vector_type(4))) short short4_;
typedef __attribute__((ext_vector_type(4))) float f32x4;

#define MFMA16(a, b, c) __builtin_amdgcn_mfma_f32_16x16x32_bf16((a), (b), (c), 0, 0, 0)

// Problem constants
#define BATCH 2
#define NQ 2048
#define NKV 2048
#define HEADS 8
#define DHEAD 64
#define CQ 1024
#define CK 768
#define IDIM 512   // HEADS*DHEAD
#define SCALE 0.125f

__device__ __forceinline__ short8 ld8(const bf16* p) {
    return *(const short8*)p;
}

// async global->LDS, 16 bytes per lane. LDS dst must be wave-uniform base + lane*16.
__device__ __forceinline__ void async_ld16(const bf16* g, bf16* l) {
    __builtin_amdgcn_global_load_lds((__attribute__((address_space(1))) const void*)g,
                                     (__attribute__((address_space(3))) void*)l,
                                     16, 0, 0);
}

__device__ __forceinline__ unsigned int pk2(float a, float b) {
    union { bf16 h[2]; unsigned int u; } x;
    x.h[0] = __float2bfloat16(a);
    x.h[1] = __float2bfloat16(b);
    return x.u;
}

// ---------------------------------------------------------------------------
// Prologue: fp32->bf16 activation pack (blocks 0..3583, 8 floats/thread) +
// tiled weight transpose fp32(R,C) -> bf16(C,R) (blocks 3584..4031).
// ---------------------------------------------------------------------------
__global__ __launch_bounds__(256) void prologue(
    const float* __restrict__ x, const float* __restrict__ ctx,
    const float* __restrict__ Wq, const float* __restrict__ Wk,
    const float* __restrict__ Wv, const float* __restrict__ Wo,
    bf16* __restrict__ Xb, bf16* __restrict__ Cb,
    bf16* __restrict__ WqT, bf16* __restrict__ WkT,
    bf16* __restrict__ WvT, bf16* __restrict__ WoT) {
    __shared__ float tile[64][65];
    const int t = threadIdx.x;
    const int bx = blockIdx.x;

    if (bx < 3584) {
        int idx = bx * 256 + t;
        const int NX8 = (4096 * 1024) / 8;      // 524,288
        const float4* srcp;
        bf16* dstp;
        if (idx < NX8) {
            srcp = (const float4*)x + (size_t)idx * 2;
            dstp = Xb + (size_t)idx * 8;
        } else {
            int j = idx - NX8;                  // < 393,216
            srcp = (const float4*)ctx + (size_t)j * 2;
            dstp = Cb + (size_t)j * 8;
        }
        float4 v0 = srcp[0], v1 = srcp[1];
        bf16 tmp[8] = {__float2bfloat16(v0.x), __float2bfloat16(v0.y),
                       __float2bfloat16(v0.z), __float2bfloat16(v0.w),
                       __float2bfloat16(v1.x), __float2bfloat16(v1.y),
                       __float2bfloat16(v1.z), __float2bfloat16(v1.w)};
        *(short8*)dstp = *(short8*)tmp;
        return;
    }

    int tb = bx - 3584;   // 0..447
    const float* src; bf16* dst; int R, C, ti;
    if (tb < 128)      { src = Wq; dst = WqT; R = 1024; C = 512;  ti = tb; }
    else if (tb < 224) { src = Wk; dst = WkT; R = 768;  C = 512;  ti = tb - 128; }
    else if (tb < 320) { src = Wv; dst = WvT; R = 768;  C = 512;  ti = tb - 224; }
    else               { src = Wo; dst = WoT; R = 512;  C = 1024; ti = tb - 320; }
    const int tilesC = C >> 6;
    const int tr = ti / tilesC, tc = ti - tr * tilesC;

    {
        int row = t >> 4;
        int c4 = (t & 15) * 4;
#pragma unroll
        for (int p = 0; p < 4; ++p) {
            float4 v = *(const float4*)&src[(size_t)(tr * 64 + p * 16 + row) * C + tc * 64 + c4];
            tile[p * 16 + row][c4 + 0] = v.x;
            tile[p * 16 + row][c4 + 1] = v.y;
            tile[p * 16 + row][c4 + 2] = v.z;
            tile[p * 16 + row][c4 + 3] = v.w;
        }
    }
    __syncthreads();
    {
        int oc = t >> 2;
        int r0 = (t & 3) * 16;
        bf16 tmp[16];
#pragma unroll
        for (int j = 0; j < 16; ++j)
            tmp[j] = __float2bfloat16(tile[r0 + j][oc]);
        bf16* dp = dst + (size_t)(tc * 64 + oc) * R + tr * 64 + r0;
        *(short8*)dp = *(short8*)&tmp[0];
        *(short8*)(dp + 8) = *(short8*)&tmp[8];
    }
}

// ---------------------------------------------------------------------------
// Fused Q/K/V projection GEMM, NEW: 128x128 tiles (m97-class), BK=64,
// XOR-swizzled LDS, double-buffered, acc[4][4]/wave (32 MFMA : 16 ds_read
// per K-step). Grid (bm=32, bn=4, z=3): A-panel sharers (same bm, ids 32
// apart) land on the same XCD -> A read once per XCD.
// blockIdx.z: 0 -> Q, 1 -> K, 2 -> V^T epilogue.
// ---------------------------------------------------------------------------
__global__ __launch_bounds__(256) void qkv_gemm(
    const bf16* __restrict__ Xb, const bf16* __restrict__ Cb,
    const bf16* __restrict__ WqT, const bf16* __restrict__ WkT,
    const bf16* __restrict__ WvT,
    bf16* __restrict__ Qb, bf16* __restrict__ Kb, bf16* __restrict__ Vt) {
    __shared__ char SMEM[65536];               // At 32K + Bts 32K; epilogue aliases base
    bf16* At  = (bf16*)SMEM;                   // [2][128*64]
    bf16* Bts = (bf16*)(SMEM + 32768);         // [2][128*64]
    bf16* Ep  = (bf16*)SMEM;                   // epilogue: [128][136] bf16 (34.8 KB)

    const int z = blockIdx.z;
    const bf16* A  = (z == 0) ? Xb : Cb;
    const bf16* Bt = (z == 0) ? WqT : (z == 1) ? WkT : WvT;
    const int K = (z == 0) ? 1024 : 768;

    const int t = threadIdx.x;
    const int wave = t >> 6;
    const int lane = t & 63;
    const int n15 = lane & 15;
    const int quad = lane >> 4;
    const int wm = wave >> 1;      // 0..1
    const int wn = wave & 1;       // 0..1
    const int bm = blockIdx.x;     // 0..31 (row-tile)
    const int bn = blockIdx.y;     // 0..3  (col-tile)

    f32x4 acc[4][4] = {};

    const bf16* Ablk = A + (size_t)bm * 128 * K;
    const bf16* Bblk = Bt + (size_t)bn * 128 * K;

    // staging: 128 rows x 64 cols per matrix, 4 slots/thread each
    int sr[4], sc[4];
#pragma unroll
    for (int i = 0; i < 4; ++i) {
        int g = i * 256 + t;
        sr[i] = g >> 3; sc[i] = ((g & 7) ^ (sr[i] & 7)) * 8;
    }

#pragma unroll
    for (int i = 0; i < 4; ++i)
        async_ld16(Ablk + sr[i] * K + sc[i], At + (i * 256 + t) * 8);
#pragma unroll
    for (int i = 0; i < 4; ++i)
        async_ld16(Bblk + sr[i] * K + sc[i], Bts + (i * 256 + t) * 8);
    __syncthreads();

    for (int k0 = 0; k0 < K; k0 += 64) {
        const int p = (k0 >> 6) & 1;
        if (k0 + 64 < K) {
            const int q = p ^ 1;
            const int kn = k0 + 64;
#pragma unroll
            for (int i = 0; i < 4; ++i)
                async_ld16(Ablk + sr[i] * K + kn + sc[i], At + q * 8192 + (i * 256 + t) * 8);
#pragma unroll
            for (int i = 0; i < 4; ++i)
                async_ld16(Bblk + sr[i] * K + kn + sc[i], Bts + q * 8192 + (i * 256 + t) * 8);
        }

#pragma unroll
        for (int kh = 0; kh < 2; ++kh) {
            short8 af[4], bfr[4];
#pragma unroll
            for (int mt = 0; mt < 4; ++mt) {
                int R = wm * 64 + mt * 16 + n15;
                af[mt] = ld8(At + p * 8192 + R * 64 + (((kh * 4 + quad) ^ (R & 7)) * 8));
            }
#pragma unroll
            for (int nt = 0; nt < 4; ++nt) {
                int R = wn * 64 + nt * 16 + n15;
                bfr[nt] = ld8(Bts + p * 8192 + R * 64 + (((kh * 4 + quad) ^ (R & 7)) * 8));
            }
#pragma unroll
            for (int mt = 0; mt < 4; ++mt)
#pragma unroll
                for (int nt = 0; nt < 4; ++nt)
                    acc[mt][nt] = MFMA16(af[mt], bfr[nt], acc[mt][nt]);
        }

        __syncthreads();   // compiler drains vmcnt here -> next buffer ready
    }

    // -------- epilogue: stage to LDS, store coalesced (short8) --------
    if (z < 2) {
        // row-major [128][136]
#pragma unroll
        for (int mt = 0; mt < 4; ++mt)
#pragma unroll
            for (int nt = 0; nt < 4; ++nt) {
                int col = wn * 64 + nt * 16 + n15;
#pragma unroll
                for (int r = 0; r < 4; ++r) {
                    int row = wm * 64 + mt * 16 + quad * 4 + r;
                    Ep[row * 136 + col] = __float2bfloat16(acc[mt][nt][r]);
                }
            }
    } else {
        // transposed [128 cols][136] so j is contiguous for Vt
#pragma unroll
        for (int mt = 0; mt < 4; ++mt)
#pragma unroll
            for (int nt = 0; nt < 4; ++nt) {
                int col = wn * 64 + nt * 16 + n15;
#pragma unroll
                for (int r = 0; r < 4; ++r) {
                    int row = wm * 64 + mt * 16 + quad * 4 + r;
                    Ep[col * 136 + row] = __float2bfloat16(acc[mt][nt][r]);
                }
            }
    }
    __syncthreads();

    bf16* C = (z == 0) ? Qb : (z == 1) ? Kb : Vt;
    if (z < 2) {
#pragma unroll
        for (int i = 0; i < 8; ++i) {
            int idx = i * 256 + t;
            int row = idx >> 4, seg = idx & 15;
            short8 v = ld8(&Ep[row * 136 + seg * 8]);
            *(short8*)&C[(size_t)(bm * 128 + row) * 512 + bn * 128 + seg * 8] = v;
        }
    } else {
        const int bb = bm >> 4;   // batch of this 128-row block (2048 rows/batch)
#pragma unroll
        for (int i = 0; i < 8; ++i) {
            int idx = i * 256 + t;
            int col = idx >> 4, seg = idx & 15;
            int cg = bn * 128 + col;
            int hh = cg >> 6, dd = cg & 63;
            int jrow = (bm & 15) * 128 + seg * 8;   // within-batch key index
            short8 v = ld8(&Ep[col * 136 + seg * 8]);
            *(short8*)&C[(size_t)(((bb << 3) + hh) * 64 + dd) * 2048 + jrow] = v;
        }
    }
}

// ---------------------------------------------------------------------------
// Final GEMM: out(4096,1024) = Ob(4096,512) @ WoT(1024,512)^T + bo, fp32 out.
// NEW: 128x128 tiles, BK=64, swizzled, double-buffered; fp32 epilogue in two
// 64-row passes through LDS [64][132] (fits 64 KB budget). Grid (bm=32,bn=8):
// A-panel sharers co-XCD.
// ---------------------------------------------------------------------------
__global__ __launch_bounds__(256) void out_gemm(const bf16* __restrict__ A,
                                                const bf16* __restrict__ Bt,
                                                const float* __restrict__ bias,
                                                float* __restrict__ C) {
    const int K = 512, N = 1024;
    __shared__ char SMEM[65536];
    bf16* At  = (bf16*)SMEM;                   // [2][128*64]
    bf16* Bts = (bf16*)(SMEM + 32768);         // [2][128*64]
    float* Ep = (float*)SMEM;                  // epilogue: [64][132] fp32 (33.8 KB)

    const int t = threadIdx.x;
    const int wave = t >> 6;
    const int lane = t & 63;
    const int n15 = lane & 15;
    const int quad = lane >> 4;
    const int wm = wave >> 1;
    const int wn = wave & 1;
    const int bm = blockIdx.x;     // 0..31
    const int bn = blockIdx.y;     // 0..7

    f32x4 acc[4][4] = {};

    const bf16* Ablk = A + (size_t)bm * 128 * K;
    const bf16* Bblk = Bt + (size_t)bn * 128 * K;

    int sr[4], sc[4];
#pragma unroll
    for (int i = 0; i < 4; ++i) {
        int g = i * 256 + t;
        sr[i] = g >> 3; sc[i] = ((g & 7) ^ (sr[i] & 7)) * 8;
    }

#pragma unroll
    for (int i = 0; i < 4; ++i)
        async_ld16(Ablk + sr[i] * K + sc[i], At + (i * 256 + t) * 8);
#pragma unroll
    for (int i = 0; i < 4; ++i)
        async_ld16(Bblk + sr[i] * K + sc[i], Bts + (i * 256 + t) * 8);
    __syncthreads();

    for (int k0 = 0; k0 < K; k0 += 64) {
        const int p = (k0 >> 6) & 1;
        if (k0 + 64 < K) {
            const int q = p ^ 1;
            const int kn = k0 + 64;
#pragma unroll
            for (int i = 0; i < 4; ++i)
                async_ld16(Ablk + sr[i] * K + kn + sc[i], At + q * 8192 + (i * 256 + t) * 8);
#pragma unroll
            for (int i = 0; i < 4; ++i)
                async_ld16(Bblk + sr[i] * K + kn + sc[i], Bts + q * 8192 + (i * 256 + t) * 8);
        }

#pragma unroll
        for (int kh = 0; kh < 2; ++kh) {
            short8 af[4], bfr[4];
#pragma unroll
            for (int mt = 0; mt < 4; ++mt) {
                int R = wm * 64 + mt * 16 + n15;
                af[mt] = ld8(At + p * 8192 + R * 64 + (((kh * 4 + quad) ^ (R & 7)) * 8));
            }
#pragma unroll
            for (int nt = 0; nt < 4; ++nt) {
                int R = wn * 64 + nt * 16 + n15;
                bfr[nt] = ld8(Bts + p * 8192 + R * 64 + (((kh * 4 + quad) ^ (R & 7)) * 8));
            }
#pragma unroll
            for (int mt = 0; mt < 4; ++mt)
#pragma unroll
                for (int nt = 0; nt < 4; ++nt)
                    acc[mt][nt] = MFMA16(af[mt], bfr[nt], acc[mt][nt]);
        }

        __syncthreads();
    }

    // fp32 epilogue, two 64-row passes (waves wm==half own the rows)
#pragma unroll
    for (int half = 0; half < 2; ++half) {
        if (wm == half) {
#pragma unroll
            for (int mt = 0; mt < 4; ++mt)
#pragma unroll
                for (int nt = 0; nt < 4; ++nt) {
                    int col = wn * 64 + nt * 16 + n15;
#pragma unroll
                    for (int r = 0; r < 4; ++r) {
                        int row = mt * 16 + quad * 4 + r;   // local 0..63
                        Ep[row * 132 + col] = acc[mt][nt][r];
                    }
                }
        }
        __syncthreads();
#pragma unroll
        for (int i = 0; i < 8; ++i) {
            int f4 = i * 256 + t;
            int row = f4 >> 5;            // 0..63
            int c4 = (f4 & 31) * 4;       // 0..124
            float4 v = *(float4*)&Ep[row * 132 + c4];
            float4 bv = *(const float4*)&bias[bn * 128 + c4];
            v.x += bv.x; v.y += bv.y; v.z += bv.z; v.w += bv.w;
            *(float4*)&C[(size_t)(bm * 128 + half * 64 + row) * N + bn * 128 + c4] = v;
        }
        __syncthreads();   // pass-0 reads done before pass-1 overwrites
    }
}

// ---------------------------------------------------------------------------
// Flash attention (verified r2): double-buffered K/V tiles, one barrier per
// 64-key iteration, P fully in registers with permuted PV key order.
//  Q:(b,i,h,d)  K:(b,j,h,d)  Vt:(b,h,d,j)  O:(b,i,h,d)
// ---------------------------------------------------------------------------
__global__ __launch_bounds__(512, 4) void flash_attn(const bf16* __restrict__ Q,
                                                     const bf16* __restrict__ K,
                                                     const bf16* __restrict__ Vt,
                                                     bf16* __restrict__ O) {
    __shared__ bf16 Kt[2][2][64 * 64];      // [buf][khalf] swizzled K tile (32 KB)
    __shared__ bf16 Vte[2][2][64 * 64];     // [buf][khalf] swizzled V^T tile (32 KB)
    // epilogue aliases (only touched after the post-loop barrier):
    float* Oc = (float*)&Kt[0][0][0];                    // [4][64][16] fp32 partial O
    float* Lc = (float*)((char*)&Kt[0][0][0] + 16384);   // [4][16] partial l
    bf16*  Pe = &Vte[0][0][0];                           // [4][16*72] O staging

    const int t = threadIdx.x;
    const int wave = t >> 6;            // 0..7
    const int g = wave >> 1;            // q-group 0..3
    const int khalf = wave & 1;         // key half
    const int lane = t & 63;
    const int n15 = lane & 15;
    const int quad = lane >> 4;

    const int L = blockIdx.x;           // 0..511
    const int bh = L & 15;              // XCD = L%8 -> bh%8: 2 (b,h) per XCD
    const int b = bh >> 3, h = bh & 7;
    const int q0 = (L >> 4) * 64;
    const int qw = q0 + g * 16;

    const bf16* Qp = Q + ((size_t)(b * NQ + qw) * IDIM + h * DHEAD);
    const bf16* Kp = K + ((size_t)b * NKV * IDIM + h * DHEAD)
                       + (size_t)(khalf * 1024) * IDIM;
    const bf16* Vp = Vt + (size_t)((b * HEADS + h) * DHEAD) * NKV + khalf * 1024;

    // Q fragments (B-operand): B[n=q=lane&15][k=d=quad*8+j], two 32-d halves
    short8 qa0 = ld8(Qp + n15 * IDIM + quad * 8);
    short8 qa1 = ld8(Qp + n15 * IDIM + 32 + quad * 8);

    // staging (256 lanes per half): slot s -> row r = s>>3, chunk c = (s&7)^(r&7)
    const int s0 = g * 128 + lane;
    const int s1 = s0 + 64;
    const int r0 = s0 >> 3, c0 = (s0 & 7) ^ (r0 & 7);
    const int r1 = s1 >> 3, c1 = (s1 & 7) ^ (r1 & 7);
    const bf16* kg0 = Kp + r0 * IDIM + c0 * 8;
    const bf16* kg1 = Kp + r1 * IDIM + c1 * 8;
    const bf16* vg0 = Vp + (size_t)r0 * NKV + c0 * 8;
    const bf16* vg1 = Vp + (size_t)r1 * NKV + c1 * 8;

    f32x4 o[4] = {};
    float lsum = 0.f;
    const int sw = n15 & 7;
    const int qh = quad >> 1;           // half-chunk select for paired V reads
    const int qb = (quad & 1) << 2;     // 4-elem offset within chunk

    // prologue: stage tile 0 into buf 0
    async_ld16(kg0, &Kt[0][khalf][s0 * 8]);
    async_ld16(kg1, &Kt[0][khalf][s1 * 8]);
    async_ld16(vg0, &Vte[0][khalf][s0 * 8]);
    async_ld16(vg1, &Vte[0][khalf][s1 * 8]);

    for (int it = 0; it < 16; ++it) {
        const int cur = it & 1;
        // current tile's DMA must have landed (drain), everyone off buf[cur^1]
        asm volatile("s_waitcnt vmcnt(0)" ::: "memory");
        __syncthreads();
        if (it < 15) {
            const int kn = (it + 1) * 64;
            async_ld16(kg0 + (size_t)kn * IDIM, &Kt[cur ^ 1][khalf][s0 * 8]);
            async_ld16(kg1 + (size_t)kn * IDIM, &Kt[cur ^ 1][khalf][s1 * 8]);
            async_ld16(vg0 + kn, &Vte[cur ^ 1][khalf][s0 * 8]);
            async_ld16(vg1 + kn, &Vte[cur ^ 1][khalf][s1 * 8]);
        }

        // S^T = K * Q^T : A=K frag A[m=key16][k=d], B=Q. 4 key-subtiles.
        f32x4 s[4] = {};
#pragma unroll
        for (int su = 0; su < 4; ++su) {
            const bf16* kr = &Kt[cur][khalf][(su * 16 + n15) * 64];
            short8 ka0 = ld8(kr + ((quad ^ sw) * 8));
            short8 ka1 = ld8(kr + (((4 + quad) ^ sw) * 8));
            s[su] = MFMA16(ka0, qa0, s[su]);
            s[su] = MFMA16(ka1, qa1, s[su]);
        }

        // p = exp(s*SCALE); pack to bf16 pairs fully in-register.
        // lane holds P^T[key = su*16 + quad*4 + r][q = n15]
        unsigned int w[4][2];
#pragma unroll
        for (int su = 0; su < 4; ++su) {
            float p0 = __expf(s[su][0] * SCALE);
            float p1 = __expf(s[su][1] * SCALE);
            float p2 = __expf(s[su][2] * SCALE);
            float p3 = __expf(s[su][3] * SCALE);
            lsum += (p0 + p1) + (p2 + p3);
            w[su][0] = pk2(p0, p1);
            w[su][1] = pk2(p2, p3);
        }
        // PV B-operand with permuted key order sigma(quad,j):
        //   pb0: keys {4q..4q+3 (su0), 16+4q..16+4q+3 (su1)}  (32-key half A)
        //   pb1: keys {32+4q.. (su2), 48+4q.. (su3)}           (32-key half B)
        union { short8 v; unsigned int u[4]; } pb0, pb1;
        pb0.u[0] = w[0][0]; pb0.u[1] = w[0][1]; pb0.u[2] = w[1][0]; pb0.u[3] = w[1][1];
        pb1.u[0] = w[2][0]; pb1.u[1] = w[2][1]; pb1.u[2] = w[3][0]; pb1.u[3] = w[3][1];

        // O^T += V^T * P^T : A=V frag A[m=d16][k], V columns fetched in the
        // SAME permuted key order via paired b64 reads at half-chunks.
#pragma unroll
        for (int d4 = 0; d4 < 4; ++d4) {
            const bf16* vr = &Vte[cur][khalf][(d4 * 16 + n15) * 64];
            union { short8 v; short4_ hh[2]; } va0, va1;
            va0.hh[0] = *(const short4_*)(vr + (((qh    ) ^ sw) << 3) + qb); // keys 4q+0..3
            va0.hh[1] = *(const short4_*)(vr + (((qh | 2) ^ sw) << 3) + qb); // keys 16+4q
            va1.hh[0] = *(const short4_*)(vr + (((qh | 4) ^ sw) << 3) + qb); // keys 32+4q
            va1.hh[1] = *(const short4_*)(vr + (((qh | 6) ^ sw) << 3) + qb); // keys 48+4q
            o[d4] = MFMA16(va0.v, pb0.v, o[d4]);
            o[d4] = MFMA16(va1.v, pb1.v, o[d4]);
        }
        // no trailing barrier: next iteration's barrier protects buf swap
    }

    // per-wave l reduction over quads -> all lanes of same n15 hold l[q]
    lsum += __shfl_xor(lsum, 16, 64);
    lsum += __shfl_xor(lsum, 32, 64);

    __syncthreads();   // all waves done with K/V tiles; safe to alias LDS

    // combine key halves (additive partials — no max subtraction)
    if (khalf == 1) {
#pragma unroll
        for (int d4 = 0; d4 < 4; ++d4)
#pragma unroll
            for (int r = 0; r < 4; ++r)
                Oc[(g * 64 + d4 * 16 + quad * 4 + r) * 16 + n15] = o[d4][r];
        if (quad == 0) Lc[g * 16 + n15] = lsum;
    }
    __syncthreads();
    if (khalf == 0) {
        float lt = lsum + Lc[g * 16 + n15];
        float inv = 1.0f / lt;
#pragma unroll
        for (int d4 = 0; d4 < 4; ++d4) {
            bf16 pk[4];
#pragma unroll
            for (int r = 0; r < 4; ++r) {
                float v = o[d4][r] + Oc[(g * 64 + d4 * 16 + quad * 4 + r) * 16 + n15];
                pk[r] = __float2bfloat16(v * inv);
            }
            *(uint2*)&Pe[g * (16 * 72) + n15 * 72 + d4 * 16 + quad * 4] = *(uint2*)pk;
        }
    }
    __syncthreads();

    // coalesced O store: thread t -> q_local = t>>3 (64 rows), 8 d-elems (16B)
    {
        int ql = t >> 3, seg = t & 7;
        const bf16* src = &Pe[(ql >> 4) * (16 * 72) + (ql & 15) * 72 + seg * 8];
        short8 a0 = ld8(src);
        bf16* dst = O + ((size_t)(b * NQ + q0 + ql) * IDIM + h * DHEAD + seg * 8);
        *(short8*)dst = a0;
    }
}

// ---------------------------------------------------------------------------
extern "C" void kernel_launch(void* const* d_in, const int* in_sizes, int n_in,
                              void* d_out, int out_size, void* d_ws, size_t ws_size,
                              hipStream_t stream) {
    (void)in_sizes; (void)n_in; (void)out_size; (void)ws_size;

    const float* x   = (const float*)d_in[0];   // (2,2048,1024)
    const float* ctx = (const float*)d_in[1];   // (2,2048,768)
    const float* Wq  = (const float*)d_in[2];   // (1024,512)
    const float* Wk  = (const float*)d_in[3];   // (768,512)
    const float* Wv  = (const float*)d_in[4];   // (768,512)
    const float* Wo  = (const float*)d_in[5];   // (512,1024)
    const float* bo  = (const float*)d_in[6];   // (1024,)
    float* out = (float*)d_out;                 // (2,2048,1024) fp32

    char* ws = (char*)d_ws;
    bf16* Xb  = (bf16*)(ws + 0);           // 4096x1024 bf16 : 8,388,608 B
    bf16* Cb  = (bf16*)(ws + 8388608);     // 4096x768  bf16 : 6,291,456 B
    bf16* WqT = (bf16*)(ws + 14680064);    //  512x1024 : 1,048,576 B
    bf16* WkT = (bf16*)(ws + 15728640);    //  512x768  :   786,432 B
    bf16* WvT = (bf16*)(ws + 16515072);    //  512x768  :   786,432 B
    bf16* WoT = (bf16*)(ws + 17301504);    // 1024x512  : 1,048,576 B
    bf16* Qb  = (bf16*)(ws + 18350080);    // 4096x512  : 4,194,304 B
    bf16* Kb  = (bf16*)(ws + 22544384);    // 4096x512  : 4,194,304 B
    bf16* Vt  = (bf16*)(ws + 26738688);    // (2,8,64,2048) : 4,194,304 B
    bf16* Ob  = (bf16*)(ws + 30932992);    // 4096x512  : 4,194,304 B
    // total 35,127,296 B

    prologue<<<4032, 256, 0, stream>>>(x, ctx, Wq, Wk, Wv, Wo,
                                       Xb, Cb, WqT, WkT, WvT, WoT);

    // Q/K/V projections: 128x128 tiles, BK=64, 384 blocks, double-buffered
    qkv_gemm<<<dim3(32, 4, 3), 256, 0, stream>>>(Xb, Cb, WqT, WkT, WvT, Qb, Kb, Vt);

    // attention: 512 blocks x 512 threads (8 waves: 4 q-groups x 2 key-halves)
    flash_attn<<<512, 512, 0, stream>>>(Qb, Kb, Vt, Ob);

    // out = O @ Wo + bo, fp32: 128x128 tiles, BK=64, 256 blocks
    out_gemm<<<dim3(32, 8), 256, 0, stream>>>(Ob, WoT, bo, out);
}